// Round 10
// baseline (215.289 us; speedup 1.0000x reference)
//
#include <hip/hip_runtime.h>
#include <hip/hip_bf16.h>
#include <math.h>

// Shapes: B=4, N=1024, D=768, H=12, hd=64
constexpr int NSeq = 1024;
constexpr int DIM  = 768;
constexpr int NH   = 12;
constexpr int HD   = 64;

// exp2-domain softmax constants
#define LOG2E     1.4426950408889634f
#define QSCALE    0.18033688011112042f   /* 0.125 * log2e */
#define BSHIFT    11.541560327111707f    /* 8 * log2e */
#define EBQ       6551.278150676693f     /* log2e * 4541 (16-bit quant scale) */
#define EBDEC     (-1.0f / 4541.0f)

#if __has_builtin(__builtin_amdgcn_exp2f)
#define EXP2F(x) __builtin_amdgcn_exp2f(x)
#else
#define EXP2F(x) exp2f(x)
#endif

typedef __attribute__((ext_vector_type(8))) short bf16x8;   // 8 bf16 (4 VGPRs)
typedef __attribute__((ext_vector_type(4))) float f32x4;

// fp32 -> bf16 RNE (scalar)
__device__ __forceinline__ short f2b(float f) {
    unsigned u = __float_as_uint(f);
    unsigned r = (u + 0x7fffu + ((u >> 16) & 1u)) >> 16;
    return (short)r;
}
// packed pair via native v_cvt_pk_bf16_f32
__device__ __forceinline__ unsigned pk2(float a, float b) {
    __hip_bfloat162 h = __float22bfloat162_rn(float2{a, b});
    return *reinterpret_cast<unsigned*>(&h);
}

// async global->LDS, 16B per lane. LDS dest = uniform base + lane*16.
__device__ __forceinline__ void glds16(const short* g, short* l) {
    __builtin_amdgcn_global_load_lds(
        (const __attribute__((address_space(1))) void*)g,
        (__attribute__((address_space(3))) void*)l, 16, 0, 0);
}

// T5 bucket, integer-exact thresholds (validated round 1)
__device__ __forceinline__ int rel_bucket(int rel) {
    int n = -rel;
    int ret = (n < 0) ? 16 : 0;
    n = (n < 0) ? -n : n;
    int k;
    if (n < 8) {
        k = n;
    } else {
        k = 8 + (n >= 12) + (n >= 16) + (n >= 23) + (n >= 32)
              + (n >= 46) + (n >= 64) + (n >= 91);
        if (k > 15) k = 15;
    }
    return ret + k;
}

// ---------------------------------------------------------------------------
// Fused prep (unchanged from R9):
//   upack      [0, 2048)    | cast [2048, 5120) | transposes [5120, 5696)
constexpr int PREP_UP   = 2048;
constexpr int PREP_CE   = PREP_UP + 3072;     // 5120
constexpr int PREP_TOT  = PREP_CE + 576;      // 5696

__global__ __launch_bounds__(256) void prep_kernel(
    const float* __restrict__ x, short* __restrict__ xb,
    const float* __restrict__ Wqkv, short* __restrict__ wqkvT,
    const float* __restrict__ Wproj, short* __restrict__ wprojT,
    const float* __restrict__ coords, const float* __restrict__ elev,
    const float* __restrict__ alpha_p, unsigned int* __restrict__ U)
{
    __shared__ float t[32][33];
    const int bx  = blockIdx.x;
    const int tid = threadIdx.x;

    if (bx < PREP_UP) {
        const int b    = bx >> 9;
        const int rem  = bx & 511;
        const int i16  = rem >> 3;
        const int jtp  = rem & 7;
        const int blk  = b * 64 + i16;
        const int lane = tid & 63, wv = tid >> 6;
        const int L = lane & 15, Q = lane >> 4;
        const float alpha = alpha_p[0];

        const int i = (i16 << 4) + L;
        const float2 cf = *(const float2*)&coords[(((size_t)b << 10) + i) * 2];
        const int cix = (int)(cf.x * 128.0f);
        const int ciy = (int)(cf.y * 128.0f);
        const float er = elev[((size_t)b << 10) + i];
        const int jt = jtp * 2 + (wv >> 1);
#pragma unroll
        for (int nth = 0; nth < 2; ++nth) {
            const int nt = (wv & 1) * 2 + nth;
            const int j0q = jt * 64 + nt * 16 + Q * 4;
            float4 c01 = *(const float4*)&coords[(((size_t)b << 10) + j0q) * 2];
            float4 c23 = *(const float4*)&coords[(((size_t)b << 10) + j0q + 2) * 2];
            float4 ej  = *(const float4*)&elev[((size_t)b << 10) + j0q];
            const float cjx[4] = {c01.x, c01.z, c23.x, c23.z};
            const float cjy[4] = {c01.y, c01.w, c23.y, c23.w};
            const float ejv[4] = {ej.x, ej.y, ej.z, ej.w};
            unsigned int uo[4];
#pragma unroll
            for (int reg = 0; reg < 4; ++reg) {
                int bk = rel_bucket(cix - (int)(cjx[reg] * 128.0f)) * 32
                       + rel_bucket(ciy - (int)(cjy[reg] * 128.0f));
                float ebp = fminf(10.0f,
                    fmaxf(0.0f, alpha * fmaxf((ejv[reg] - er) * 0.001f, 0.0f)));
                unsigned int q = (unsigned int)lrintf(ebp * EBQ);
                uo[reg] = (unsigned int)bk | (q << 16);
            }
            size_t base = ((((size_t)blk * 16 + jt) * 4 + nt) * 64 + lane) * 4;
            *(uint4*)(U + base) = make_uint4(uo[0], uo[1], uo[2], uo[3]);
        }
        return;
    }
    if (bx < PREP_CE) {
        int i = ((bx - PREP_UP) * 256 + tid) * 4;
        float4 v = *(const float4*)(x + i);
        *(short4*)(xb + i) = make_short4(f2b(v.x), f2b(v.y), f2b(v.z), f2b(v.w));
        return;
    }
    {
        const int bxx = bx - PREP_CE;          // 0..575
#pragma unroll
        for (int tt = 0; tt < 4; ++tt) {
            const int tile = bxx * 4 + tt;     // 0..2303
            const float* W; short* WT; int K, Nw, idx;
            if (tile < 1728) { W = Wqkv;  WT = wqkvT;  K = DIM; Nw = 3 * DIM; idx = tile; }
            else             { W = Wproj; WT = wprojT; K = DIM; Nw = DIM;     idx = tile - 1728; }
            const int ntl = idx % (Nw / 32), ktl = idx / (Nw / 32);
            const int k0 = ktl * 32, n0 = ntl * 32;
            const int tx = tid & 31, ty = tid >> 5;
            __syncthreads();
#pragma unroll
            for (int r = 0; r < 4; ++r)
                t[ty + r * 8][tx] = W[(size_t)(k0 + ty + r * 8) * Nw + n0 + tx];
            __syncthreads();
#pragma unroll
            for (int r = 0; r < 4; ++r)
                WT[(size_t)(n0 + ty + r * 8) * K + k0 + tx] = f2b(t[tx][ty + r * 8]);
        }
    }
}

// ---------------------------------------------------------------------------
// bf16 MFMA GEMM (unchanged from R9): 64x128 tile, BK=64, glds+XOR swizzle,
// EPI=0 LDS-staged coalesced scatter, EPI=1 fp32 + bias.
template <int EPI>
__global__ __launch_bounds__(256) void gemm_mfma(
    const short* __restrict__ A, const short* __restrict__ BT,
    const float* __restrict__ bias, float* __restrict__ Cout,
    short* __restrict__ qh, short* __restrict__ kh, short* __restrict__ vt,
    int M, int N, int K)
{
    __shared__ short SH[64 * 64 + 128 * 64];   // As (8 KB) | Bs (16 KB)
    short* As = SH;
    short* Bs = SH + 64 * 64;

    const int tid  = threadIdx.x;
    const int lane = tid & 63;
    const int wave = tid >> 6;
    const int L = lane & 15, Q = lane >> 4;
    const int m0b = blockIdx.y * 64, n0b = blockIdx.x * 128;
    const int mw = (wave >> 1) * 32;
    const int nw = (wave & 1) * 64;

    size_t aoff[2]; int la[2];
#pragma unroll
    for (int t = 0; t < 2; ++t) {
        int s = wave * 128 + t * 64 + lane;
        int r = s >> 3, c = (s & 7) ^ (r & 7);
        aoff[t] = (size_t)(m0b + r) * K + c * 8;
        la[t] = (wave * 128 + t * 64) * 8;
    }
    size_t boff[4]; int lb[4];
#pragma unroll
    for (int t = 0; t < 4; ++t) {
        int s = wave * 256 + t * 64 + lane;
        int r = s >> 3, c = (s & 7) ^ (r & 7);
        boff[t] = (size_t)(n0b + r) * K + c * 8;
        lb[t] = (wave * 256 + t * 64) * 8;
    }

    f32x4 acc[2][4];
#pragma unroll
    for (int i = 0; i < 2; ++i)
#pragma unroll
        for (int j = 0; j < 4; ++j) acc[i][j] = (f32x4){0.f, 0.f, 0.f, 0.f};

    for (int k0 = 0; k0 < K; k0 += 64) {
        __syncthreads();
#pragma unroll
        for (int t = 0; t < 2; ++t) glds16(A + aoff[t] + k0, As + la[t]);
#pragma unroll
        for (int t = 0; t < 4; ++t) glds16(BT + boff[t] + k0, Bs + lb[t]);
        __syncthreads();
#pragma unroll
        for (int ks = 0; ks < 2; ++ks) {
            bf16x8 af[2], bfr[4];
#pragma unroll
            for (int mt = 0; mt < 2; ++mt) {
                int r = mw + mt * 16 + L;
                af[mt] = *(const bf16x8*)(As + (r * 8 + ((ks * 4 + Q) ^ (r & 7))) * 8);
            }
#pragma unroll
            for (int nt = 0; nt < 4; ++nt) {
                int r = nw + nt * 16 + L;
                bfr[nt] = *(const bf16x8*)(Bs + (r * 8 + ((ks * 4 + Q) ^ (r & 7))) * 8);
            }
#pragma unroll
            for (int mt = 0; mt < 2; ++mt)
#pragma unroll
                for (int nt = 0; nt < 4; ++nt)
                    acc[mt][nt] = __builtin_amdgcn_mfma_f32_16x16x32_bf16(
                        af[mt], bfr[nt], acc[mt][nt], 0, 0, 0);
        }
    }

    const int m0 = m0b + mw, n0 = n0b + nw;
    if (EPI == 1) {
#pragma unroll
        for (int nt = 0; nt < 4; ++nt) {
            const int col = n0 + nt * 16 + L;
            const float bv = bias[col];
#pragma unroll
            for (int mt = 0; mt < 2; ++mt) {
                const int r0 = m0 + mt * 16 + Q * 4;
#pragma unroll
                for (int reg = 0; reg < 4; ++reg)
                    Cout[(size_t)(r0 + reg) * N + col] = acc[mt][nt][reg] + bv;
            }
        }
    } else {
        const int sec   = n0b / DIM;          // 0=Q, 1=K, 2=V
        const int hloc  = (n0b % DIM) >> 6;
        const int bidx  = m0b >> 10;
        const int ntok0 = m0b & 1023;
        short* T = SH;
        __syncthreads();

        if (sec < 2) {
            const float qs = (sec == 0) ? QSCALE : 1.0f;
#pragma unroll
            for (int nt = 0; nt < 4; ++nt)
#pragma unroll
                for (int mt = 0; mt < 2; ++mt) {
                    int tok = mw + mt * 16 + Q * 4;
                    int col = nw + nt * 16 + L;
#pragma unroll
                    for (int reg = 0; reg < 4; ++reg)
                        T[(tok + reg) * 136 + col] = f2b(acc[mt][nt][reg] * qs);
                }
            __syncthreads();
            const int pr = tid >> 1, half = tid & 1;
            const int hh = pr >> 6, tok = pr & 63;
            short* dstb = (sec == 0 ? qh : kh)
                + (((size_t)bidx * NH + hloc + hh) * NSeq + ntok0 + tok) * HD + half * 32;
            const short* srcb = T + tok * 136 + hh * 64 + half * 32;
#pragma unroll
            for (int c = 0; c < 4; ++c)
                *(bf16x8*)(dstb + c * 8) = *(const bf16x8*)(srcb + c * 8);
        } else {
#pragma unroll
            for (int nt = 0; nt < 4; ++nt)
#pragma unroll
                for (int mt = 0; mt < 2; ++mt) {
                    int tok = mw + mt * 16 + Q * 4;
                    int col = nw + nt * 16 + L;
                    short4 pv = make_short4(f2b(acc[mt][nt][0]), f2b(acc[mt][nt][1]),
                                            f2b(acc[mt][nt][2]), f2b(acc[mt][nt][3]));
                    *(short4*)&T[col * 72 + tok] = pv;
                }
            __syncthreads();
            const int col = tid >> 1, half = tid & 1;
            const int hh = col >> 6, d = col & 63;
            short* dstb = vt
                + (((size_t)bidx * NH + hloc + hh) * HD + d) * NSeq + ntok0 + half * 32;
            const short* srcb = T + col * 72 + half * 32;
#pragma unroll
            for (int c = 0; c < 4; ++c)
                *(bf16x8*)(dstb + c * 8) = *(const bf16x8*)(srcb + c * 8);
        }
    }
}

// ---------------------------------------------------------------------------
// Transposed-S flash attention (v6.1 math, identical). i0base splits the
// i-range across two dispatches so the rocprof top-5 stops being flooded by
// one 50-us attn row and the slowest non-attn kernel becomes visible.
__global__ __launch_bounds__(256) void attn_mfma(
    const short* __restrict__ qh, const short* __restrict__ kh,
    const short* __restrict__ vt,
    const unsigned int* __restrict__ U,
    const float* __restrict__ btab_g,             // [1024][12]
    short* __restrict__ aout,                     // [4096][768] bf16
    int i0base)
{
    __shared__ short Ks[128 * 64];  // 16 KB
    __shared__ short Vs[64 * 128];  // 16 KB
    __shared__ float btab[1024];    // 4 KB
    __shared__ short P[4][16 * 72]; // 9 KB

    const int tid  = threadIdx.x;
    const int lane = tid & 63, wave = tid >> 6;
    const int L = lane & 15, Q = lane >> 4;
    const int ib = blockIdx.x + i0base;
    const int i0 = ib * 64;
    const int bh = blockIdx.y;
    const int b  = bh / NH, h = bh % NH;

    for (int p = tid; p < 1024; p += 256)
        btab[p] = btab_g[(size_t)p * NH + h] * LOG2E - BSHIFT;

    const int iw = i0 + wave * 16;

    const short* qbase = qh + ((size_t)bh * NSeq + iw + L) * HD + Q * 8;
    const bf16x8 qf0 = *(const bf16x8*)qbase;
    const bf16x8 qf1 = *(const bf16x8*)(qbase + 32);

    size_t kgo[4], vgo[4];
    int lsl[4];
#pragma unroll
    for (int t = 0; t < 4; ++t) {
        int s = wave * 256 + t * 64 + lane;            // 0..1023
        int kr = s >> 3, kc = (s & 7) ^ (kr & 7);
        kgo[t] = ((size_t)bh * NSeq + kr) * HD + kc * 8;
        int vr = s >> 4, vc = (s & 15) ^ (vr & 15);
        vgo[t] = ((size_t)bh * HD + vr) * NSeq + vc * 8;
        lsl[t] = s * 8;
    }

    const int i16g = (b * 64) + (ib * 4 + wave);
    const unsigned int* Ub = U + (size_t)i16g * 16 * 4 * 256 + lane * 4;

    float lpart = 0.0f;
    f32x4 accO[4];
#pragma unroll
    for (int t = 0; t < 4; ++t) accO[t] = (f32x4){0.f, 0.f, 0.f, 0.f};

    short* Pw = P[wave];

    for (int jt = 0; jt < 8; ++jt) {
        const int j0 = jt * 128;
        __syncthreads();
#pragma unroll
        for (int t = 0; t < 4; ++t) glds16(kh + kgo[t] + (size_t)j0 * HD, Ks + lsl[t]);
#pragma unroll
        for (int t = 0; t < 4; ++t) glds16(vt + vgo[t] + j0, Vs + lsl[t]);
        __syncthreads();

#pragma unroll
        for (int jh = 0; jh < 2; ++jh) {
            f32x4 st[4];
#pragma unroll
            for (int nt = 0; nt < 4; ++nt) {
                int r = jh * 64 + nt * 16 + L;
                bf16x8 kf0 = *(const bf16x8*)(Ks + (r * 8 + (Q ^ (L & 7))) * 8);
                bf16x8 kf1 = *(const bf16x8*)(Ks + (r * 8 + ((4 + Q) ^ (L & 7))) * 8);
                f32x4 z = (f32x4){0.f, 0.f, 0.f, 0.f};
                z = __builtin_amdgcn_mfma_f32_16x16x32_bf16(kf0, qf0, z, 0, 0, 0);
                st[nt] = __builtin_amdgcn_mfma_f32_16x16x32_bf16(kf1, qf1, z, 0, 0, 0);
            }

#pragma unroll
            for (int nt = 0; nt < 4; ++nt) {
                uint4 u = *(const uint4*)(Ub + (((size_t)jt * 2 + jh) * 4 + nt) * 256);
                const unsigned int uv[4] = {u.x, u.y, u.z, u.w};
                float pv[4];
                float ps = 0.0f;
#pragma unroll
                for (int reg = 0; reg < 4; ++reg) {
                    float arg = st[nt][reg] + btab[uv[reg] & 1023];
                    arg = fmaf((float)(uv[reg] >> 16), EBDEC, arg);
                    float p = EXP2F(arg);
                    ps += p;
                    pv[reg] = p;
                }
                lpart += ps;
                unsigned p01 = pk2(pv[0], pv[1]);
                unsigned p23 = pk2(pv[2], pv[3]);
                *(uint2*)&Pw[L * 72 + nt * 16 + Q * 4] = make_uint2(p01, p23);
            }

            bf16x8 pf0 = *(const bf16x8*)&Pw[L * 72 + Q * 8];
            bf16x8 pf1 = *(const bf16x8*)&Pw[L * 72 + 32 + Q * 8];
#pragma unroll
            for (int dt = 0; dt < 4; ++dt) {
                int r = dt * 16 + L;
                bf16x8 vf0 = *(const bf16x8*)(Vs + (r * 16 + ((jh * 8 + Q) ^ L)) * 8);
                bf16x8 vf1 = *(const bf16x8*)(Vs + (r * 16 + ((jh * 8 + 4 + Q) ^ L)) * 8);
                accO[dt] = __builtin_amdgcn_mfma_f32_16x16x32_bf16(pf0, vf0, accO[dt], 0, 0, 0);
                accO[dt] = __builtin_amdgcn_mfma_f32_16x16x32_bf16(pf1, vf1, accO[dt], 0, 0, 0);
            }
        }
    }

    lpart += __shfl_xor(lpart, 16, 64);
    lpart += __shfl_xor(lpart, 32, 64);
    float linv[4];
#pragma unroll
    for (int reg = 0; reg < 4; ++reg)
        linv[reg] = 1.0f / __shfl(lpart, Q * 4 + reg, 64);

#pragma unroll
    for (int reg = 0; reg < 4; ++reg) {
        const size_t row = (size_t)b * NSeq + iw + Q * 4 + reg;
#pragma unroll
        for (int dt = 0; dt < 4; ++dt)
            aout[row * DIM + h * HD + dt * 16 + L] = f2b(accO[dt][reg] * linv[reg]);
    }
}

// ---------------------------------------------------------------------------
extern "C" void kernel_launch(void* const* d_in, const int* in_sizes, int n_in,
                              void* d_out, int out_size, void* d_ws, size_t ws_size,
                              hipStream_t stream)
{
    const float* x      = (const float*)d_in[0];
    const float* coords = (const float*)d_in[1];
    const float* elevp  = (const float*)d_in[2];
    const float* Wqkv   = (const float*)d_in[3];
    const float* Wproj  = (const float*)d_in[4];
    const float* bproj  = (const float*)d_in[5];
    const float* btab   = (const float*)d_in[6];
    const float* alpha  = (const float*)d_in[7];
    float* out = (float*)d_out;

    char* ws = (char*)d_ws;
    short* xb     = (short*)(ws);                        // 4096x768 bf16
    short* wqkvT  = (short*)(ws + 6291456);              // 2304x768 bf16
    short* wprojT = (short*)(ws + 9830400);              // 768x768 bf16
    short* qh     = (short*)(ws + 11010048);             // [48][1024][64]
    short* kh     = (short*)(ws + 17301504);
    short* vt     = (short*)(ws + 23592960);             // [48][64][1024]
    short* aout   = (short*)(ws + 29884416);             // 4096x768 bf16
    unsigned int* U = (unsigned int*)(ws + 36175872);    // 16.78 MB packed bias
    // total ws use: 52,953,088 bytes

    const int M = 4 * NSeq;

    prep_kernel<<<dim3(PREP_TOT), 256, 0, stream>>>(
        x, xb, Wqkv, wqkvT, Wproj, wprojT, coords, elevp, alpha, U);

    gemm_mfma<0><<<dim3(3 * DIM / 128, M / 64), 256, 0, stream>>>(
        xb, wqkvT, nullptr, nullptr, qh, kh, vt, M, 3 * DIM, DIM);

    attn_mfma<<<dim3(8, 4 * NH), 256, 0, stream>>>(
        qh, kh, vt, U, btab, aout, 0);
    attn_mfma<<<dim3(8, 4 * NH), 256, 0, stream>>>(
        qh, kh, vt, U, btab, aout, 8);

    gemm_mfma<1><<<dim3(DIM / 128, M / 64), 256, 0, stream>>>(
        aout, wprojT, bproj, out, nullptr, nullptr, nullptr, M, DIM, DIM);
}

// Round 11
// 199.730 us; speedup vs baseline: 1.0779x; 1.0779x over previous
//
#include <hip/hip_runtime.h>
#include <hip/hip_bf16.h>
#include <math.h>

// Shapes: B=4, N=1024, D=768, H=12, hd=64
constexpr int NSeq = 1024;
constexpr int DIM  = 768;
constexpr int NH   = 12;
constexpr int HD   = 64;

// exp2-domain softmax constants
#define LOG2E     1.4426950408889634f
#define QSCALE    0.18033688011112042f   /* 0.125 * log2e */
#define BSHIFT    11.541560327111707f    /* 8 * log2e */
#define EBQ       6551.278150676693f     /* log2e * 4541 (16-bit quant scale) */
#define EBDEC     (-1.0f / 4541.0f)

#if __has_builtin(__builtin_amdgcn_exp2f)
#define EXP2F(x) __builtin_amdgcn_exp2f(x)
#else
#define EXP2F(x) exp2f(x)
#endif

typedef __attribute__((ext_vector_type(8))) short bf16x8;   // 8 bf16 (4 VGPRs)
typedef __attribute__((ext_vector_type(4))) float f32x4;

// fp32 -> bf16 RNE (scalar)
__device__ __forceinline__ short f2b(float f) {
    unsigned u = __float_as_uint(f);
    unsigned r = (u + 0x7fffu + ((u >> 16) & 1u)) >> 16;
    return (short)r;
}
// packed pair via native v_cvt_pk_bf16_f32
__device__ __forceinline__ unsigned pk2(float a, float b) {
    __hip_bfloat162 h = __float22bfloat162_rn(float2{a, b});
    return *reinterpret_cast<unsigned*>(&h);
}

// async global->LDS, 16B per lane. LDS dest = uniform base + lane*16.
__device__ __forceinline__ void glds16(const short* g, short* l) {
    __builtin_amdgcn_global_load_lds(
        (const __attribute__((address_space(1))) void*)g,
        (__attribute__((address_space(3))) void*)l, 16, 0, 0);
}

// T5 bucket, integer-exact thresholds (validated round 1)
__device__ __forceinline__ int rel_bucket(int rel) {
    int n = -rel;
    int ret = (n < 0) ? 16 : 0;
    n = (n < 0) ? -n : n;
    int k;
    if (n < 8) {
        k = n;
    } else {
        k = 8 + (n >= 12) + (n >= 16) + (n >= 23) + (n >= 32)
              + (n >= 46) + (n >= 64) + (n >= 91);
        if (k > 15) k = 15;
    }
    return ret + k;
}

// ---------------------------------------------------------------------------
// Fused prep (unchanged from R9):
//   upack [0, 2048) | cast [2048, 5120) | transposes [5120, 5696)
constexpr int PREP_UP   = 2048;
constexpr int PREP_CE   = PREP_UP + 3072;     // 5120
constexpr int PREP_TOT  = PREP_CE + 576;      // 5696

__global__ __launch_bounds__(256) void prep_kernel(
    const float* __restrict__ x, short* __restrict__ xb,
    const float* __restrict__ Wqkv, short* __restrict__ wqkvT,
    const float* __restrict__ Wproj, short* __restrict__ wprojT,
    const float* __restrict__ coords, const float* __restrict__ elev,
    const float* __restrict__ alpha_p, unsigned int* __restrict__ U)
{
    __shared__ float t[32][33];
    const int bx  = blockIdx.x;
    const int tid = threadIdx.x;

    if (bx < PREP_UP) {
        const int b    = bx >> 9;
        const int rem  = bx & 511;
        const int i16  = rem >> 3;
        const int jtp  = rem & 7;
        const int blk  = b * 64 + i16;
        const int lane = tid & 63, wv = tid >> 6;
        const int L = lane & 15, Q = lane >> 4;
        const float alpha = alpha_p[0];

        const int i = (i16 << 4) + L;
        const float2 cf = *(const float2*)&coords[(((size_t)b << 10) + i) * 2];
        const int cix = (int)(cf.x * 128.0f);
        const int ciy = (int)(cf.y * 128.0f);
        const float er = elev[((size_t)b << 10) + i];
        const int jt = jtp * 2 + (wv >> 1);
#pragma unroll
        for (int nth = 0; nth < 2; ++nth) {
            const int nt = (wv & 1) * 2 + nth;
            const int j0q = jt * 64 + nt * 16 + Q * 4;
            float4 c01 = *(const float4*)&coords[(((size_t)b << 10) + j0q) * 2];
            float4 c23 = *(const float4*)&coords[(((size_t)b << 10) + j0q + 2) * 2];
            float4 ej  = *(const float4*)&elev[((size_t)b << 10) + j0q];
            const float cjx[4] = {c01.x, c01.z, c23.x, c23.z};
            const float cjy[4] = {c01.y, c01.w, c23.y, c23.w};
            const float ejv[4] = {ej.x, ej.y, ej.z, ej.w};
            unsigned int uo[4];
#pragma unroll
            for (int reg = 0; reg < 4; ++reg) {
                int bk = rel_bucket(cix - (int)(cjx[reg] * 128.0f)) * 32
                       + rel_bucket(ciy - (int)(cjy[reg] * 128.0f));
                float ebp = fminf(10.0f,
                    fmaxf(0.0f, alpha * fmaxf((ejv[reg] - er) * 0.001f, 0.0f)));
                unsigned int q = (unsigned int)lrintf(ebp * EBQ);
                uo[reg] = (unsigned int)bk | (q << 16);
            }
            size_t base = ((((size_t)blk * 16 + jt) * 4 + nt) * 64 + lane) * 4;
            *(uint4*)(U + base) = make_uint4(uo[0], uo[1], uo[2], uo[3]);
        }
        return;
    }
    if (bx < PREP_CE) {
        int i = ((bx - PREP_UP) * 256 + tid) * 4;
        float4 v = *(const float4*)(x + i);
        *(short4*)(xb + i) = make_short4(f2b(v.x), f2b(v.y), f2b(v.z), f2b(v.w));
        return;
    }
    {
        const int bxx = bx - PREP_CE;          // 0..575
#pragma unroll
        for (int tt = 0; tt < 4; ++tt) {
            const int tile = bxx * 4 + tt;     // 0..2303
            const float* W; short* WT; int K, Nw, idx;
            if (tile < 1728) { W = Wqkv;  WT = wqkvT;  K = DIM; Nw = 3 * DIM; idx = tile; }
            else             { W = Wproj; WT = wprojT; K = DIM; Nw = DIM;     idx = tile - 1728; }
            const int ntl = idx % (Nw / 32), ktl = idx / (Nw / 32);
            const int k0 = ktl * 32, n0 = ntl * 32;
            const int tx = tid & 31, ty = tid >> 5;
            __syncthreads();
#pragma unroll
            for (int r = 0; r < 4; ++r)
                t[ty + r * 8][tx] = W[(size_t)(k0 + ty + r * 8) * Nw + n0 + tx];
            __syncthreads();
#pragma unroll
            for (int r = 0; r < 4; ++r)
                WT[(size_t)(n0 + ty + r * 8) * K + k0 + tx] = f2b(t[tx][ty + r * 8]);
        }
    }
}

// ---------------------------------------------------------------------------
// bf16 MFMA GEMM (unchanged from R9)
template <int EPI>
__global__ __launch_bounds__(256) void gemm_mfma(
    const short* __restrict__ A, const short* __restrict__ BT,
    const float* __restrict__ bias, float* __restrict__ Cout,
    short* __restrict__ qh, short* __restrict__ kh, short* __restrict__ vt,
    int M, int N, int K)
{
    __shared__ short SH[64 * 64 + 128 * 64];   // As (8 KB) | Bs (16 KB)
    short* As = SH;
    short* Bs = SH + 64 * 64;

    const int tid  = threadIdx.x;
    const int lane = tid & 63;
    const int wave = tid >> 6;
    const int L = lane & 15, Q = lane >> 4;
    const int m0b = blockIdx.y * 64, n0b = blockIdx.x * 128;
    const int mw = (wave >> 1) * 32;
    const int nw = (wave & 1) * 64;

    size_t aoff[2]; int la[2];
#pragma unroll
    for (int t = 0; t < 2; ++t) {
        int s = wave * 128 + t * 64 + lane;
        int r = s >> 3, c = (s & 7) ^ (r & 7);
        aoff[t] = (size_t)(m0b + r) * K + c * 8;
        la[t] = (wave * 128 + t * 64) * 8;
    }
    size_t boff[4]; int lb[4];
#pragma unroll
    for (int t = 0; t < 4; ++t) {
        int s = wave * 256 + t * 64 + lane;
        int r = s >> 3, c = (s & 7) ^ (r & 7);
        boff[t] = (size_t)(n0b + r) * K + c * 8;
        lb[t] = (wave * 256 + t * 64) * 8;
    }

    f32x4 acc[2][4];
#pragma unroll
    for (int i = 0; i < 2; ++i)
#pragma unroll
        for (int j = 0; j < 4; ++j) acc[i][j] = (f32x4){0.f, 0.f, 0.f, 0.f};

    for (int k0 = 0; k0 < K; k0 += 64) {
        __syncthreads();
#pragma unroll
        for (int t = 0; t < 2; ++t) glds16(A + aoff[t] + k0, As + la[t]);
#pragma unroll
        for (int t = 0; t < 4; ++t) glds16(BT + boff[t] + k0, Bs + lb[t]);
        __syncthreads();
#pragma unroll
        for (int ks = 0; ks < 2; ++ks) {
            bf16x8 af[2], bfr[4];
#pragma unroll
            for (int mt = 0; mt < 2; ++mt) {
                int r = mw + mt * 16 + L;
                af[mt] = *(const bf16x8*)(As + (r * 8 + ((ks * 4 + Q) ^ (r & 7))) * 8);
            }
#pragma unroll
            for (int nt = 0; nt < 4; ++nt) {
                int r = nw + nt * 16 + L;
                bfr[nt] = *(const bf16x8*)(Bs + (r * 8 + ((ks * 4 + Q) ^ (r & 7))) * 8);
            }
#pragma unroll
            for (int mt = 0; mt < 2; ++mt)
#pragma unroll
                for (int nt = 0; nt < 4; ++nt)
                    acc[mt][nt] = __builtin_amdgcn_mfma_f32_16x16x32_bf16(
                        af[mt], bfr[nt], acc[mt][nt], 0, 0, 0);
        }
    }

    const int m0 = m0b + mw, n0 = n0b + nw;
    if (EPI == 1) {
#pragma unroll
        for (int nt = 0; nt < 4; ++nt) {
            const int col = n0 + nt * 16 + L;
            const float bv = bias[col];
#pragma unroll
            for (int mt = 0; mt < 2; ++mt) {
                const int r0 = m0 + mt * 16 + Q * 4;
#pragma unroll
                for (int reg = 0; reg < 4; ++reg)
                    Cout[(size_t)(r0 + reg) * N + col] = acc[mt][nt][reg] + bv;
            }
        }
    } else {
        const int sec   = n0b / DIM;          // 0=Q, 1=K, 2=V
        const int hloc  = (n0b % DIM) >> 6;
        const int bidx  = m0b >> 10;
        const int ntok0 = m0b & 1023;
        short* T = SH;
        __syncthreads();

        if (sec < 2) {
            const float qs = (sec == 0) ? QSCALE : 1.0f;
#pragma unroll
            for (int nt = 0; nt < 4; ++nt)
#pragma unroll
                for (int mt = 0; mt < 2; ++mt) {
                    int tok = mw + mt * 16 + Q * 4;
                    int col = nw + nt * 16 + L;
#pragma unroll
                    for (int reg = 0; reg < 4; ++reg)
                        T[(tok + reg) * 136 + col] = f2b(acc[mt][nt][reg] * qs);
                }
            __syncthreads();
            const int pr = tid >> 1, half = tid & 1;
            const int hh = pr >> 6, tok = pr & 63;
            short* dstb = (sec == 0 ? qh : kh)
                + (((size_t)bidx * NH + hloc + hh) * NSeq + ntok0 + tok) * HD + half * 32;
            const short* srcb = T + tok * 136 + hh * 64 + half * 32;
#pragma unroll
            for (int c = 0; c < 4; ++c)
                *(bf16x8*)(dstb + c * 8) = *(const bf16x8*)(srcb + c * 8);
        } else {
#pragma unroll
            for (int nt = 0; nt < 4; ++nt)
#pragma unroll
                for (int mt = 0; mt < 2; ++mt) {
                    int tok = mw + mt * 16 + Q * 4;
                    int col = nw + nt * 16 + L;
                    short4 pv = make_short4(f2b(acc[mt][nt][0]), f2b(acc[mt][nt][1]),
                                            f2b(acc[mt][nt][2]), f2b(acc[mt][nt][3]));
                    *(short4*)&T[col * 72 + tok] = pv;
                }
            __syncthreads();
            const int col = tid >> 1, half = tid & 1;
            const int hh = col >> 6, d = col & 63;
            short* dstb = vt
                + (((size_t)bidx * NH + hloc + hh) * HD + d) * NSeq + ntok0 + half * 32;
            const short* srcb = T + col * 72 + half * 32;
#pragma unroll
            for (int c = 0; c < 4; ++c)
                *(bf16x8*)(dstb + c * 8) = *(const bf16x8*)(srcb + c * 8);
        }
    }
}

// ---------------------------------------------------------------------------
// Transposed-S flash attention, v7: 64-j tile (R5 verified indices) with
// j-split 2 (blockIdx.z). R10 proved attn is concurrency-starved (half-work
// dispatch at half occupancy ran the SAME 50 us): waves/CU was grid-limited
// to 12. Split doubles blocks (1536 = 6/CU grid); 29.7 KB LDS -> 5/CU
// capacity -> ~20 waves/CU. Static-shift softmax partials combine by pure
// addition: O partials atomicAdd'd into fp32 Of (memset to 0 each launch),
// per-split l in laux; combine_norm normalizes -> aout bf16.
__global__ __launch_bounds__(256) void attn_mfma(
    const short* __restrict__ qh, const short* __restrict__ kh,
    const short* __restrict__ vt,
    const unsigned int* __restrict__ U,
    const float* __restrict__ btab_g,             // [1024][12]
    float* __restrict__ Of,                       // [4096][768] fp32 accum
    float* __restrict__ laux)                     // [2][48][1024] fp32
{
    __shared__ short Ks[64 * 64];   // 8 KB, rows=j, 8 chunks/row
    __shared__ short Vs[64 * 64];   // 8 KB, rows=d, 8 chunks/row
    __shared__ float btab[1024];    // 4 KB
    __shared__ short P[4][16 * 72]; // 9 KB

    const int tid  = threadIdx.x;
    const int lane = tid & 63, wave = tid >> 6;
    const int L = lane & 15, Q = lane >> 4;
    const int ib = blockIdx.x;                  // 0..15 i-tile
    const int i0 = ib * 64;
    const int bh = blockIdx.y;
    const int sp = blockIdx.z;                  // j-split 0/1
    const int b  = bh / NH, h = bh % NH;
    const int jbase = sp * 512;

    for (int p = tid; p < 1024; p += 256)
        btab[p] = btab_g[(size_t)p * NH + h] * LOG2E - BSHIFT;

    const int iw = i0 + wave * 16;

    const short* qbase = qh + ((size_t)bh * NSeq + iw + L) * HD + Q * 8;
    const bf16x8 qf0 = *(const bf16x8*)qbase;
    const bf16x8 qf1 = *(const bf16x8*)(qbase + 32);

    // staging addresses (2 K + 2 V glds per wave per 64-j iter)
    size_t kgo[2], vgo[2];
    int lsl[2];
#pragma unroll
    for (int t = 0; t < 2; ++t) {
        int s = wave * 128 + t * 64 + lane;     // 0..511
        int r = s >> 3, c = (s & 7) ^ (r & 7);
        kgo[t] = ((size_t)bh * NSeq + jbase + r) * HD + c * 8;   // + j0*HD
        vgo[t] = ((size_t)bh * HD + r) * NSeq + jbase + c * 8;   // + j0
        lsl[t] = s * 8;
    }

    const int i16g = (b * 64) + (ib * 4 + wave);
    const unsigned int* Ub = U + (size_t)i16g * 16 * 4 * 256 + lane * 4;

    float lpart = 0.0f;
    f32x4 accO[4];
#pragma unroll
    for (int t = 0; t < 4; ++t) accO[t] = (f32x4){0.f, 0.f, 0.f, 0.f};

    short* Pw = P[wave];

    for (int jt = 0; jt < 8; ++jt) {
        const int j0 = jt * 64;
        const int jtg = sp * 8 + jt;            // global j-tile for U
        __syncthreads();                        // prev Ks/Vs reads done
#pragma unroll
        for (int t = 0; t < 2; ++t) {
            glds16(kh + kgo[t] + (size_t)j0 * HD, Ks + lsl[t]);
            glds16(vt + vgo[t] + j0, Vs + lsl[t]);
        }
        __syncthreads();                        // staged data visible

        // ---- S^T = MFMA(A=K from LDS, B=Q): C row = j-local, col = i = L
        f32x4 st[4];
#pragma unroll
        for (int nt = 0; nt < 4; ++nt) {
            int r = nt * 16 + L;
            bf16x8 kf0 = *(const bf16x8*)(Ks + (r * 8 + (Q ^ (r & 7))) * 8);
            bf16x8 kf1 = *(const bf16x8*)(Ks + (r * 8 + ((4 + Q) ^ (r & 7))) * 8);
            f32x4 z = (f32x4){0.f, 0.f, 0.f, 0.f};
            z = __builtin_amdgcn_mfma_f32_16x16x32_bf16(kf0, qf0, z, 0, 0, 0);
            st[nt] = __builtin_amdgcn_mfma_f32_16x16x32_bf16(kf1, qf1, z, 0, 0, 0);
        }

        // ---- bias + exp2 + pack P (A-layout: row i=L, col j)
#pragma unroll
        for (int nt = 0; nt < 4; ++nt) {
            uint4 u = *(const uint4*)(Ub + ((size_t)jtg * 4 + nt) * 256);
            const unsigned int uv[4] = {u.x, u.y, u.z, u.w};
            float pv[4];
            float ps = 0.0f;
#pragma unroll
            for (int reg = 0; reg < 4; ++reg) {
                float arg = st[nt][reg] + btab[uv[reg] & 1023];
                arg = fmaf((float)(uv[reg] >> 16), EBDEC, arg);
                float p = EXP2F(arg);
                ps += p;
                pv[reg] = p;
            }
            lpart += ps;
            unsigned p01 = pk2(pv[0], pv[1]);
            unsigned p23 = pk2(pv[2], pv[3]);
            *(uint2*)&Pw[L * 72 + nt * 16 + Q * 4] = make_uint2(p01, p23);
        }

        // ---- O += P V (P A-frag wave-private; V B-frag from LDS)
        bf16x8 pf0 = *(const bf16x8*)&Pw[L * 72 + Q * 8];
        bf16x8 pf1 = *(const bf16x8*)&Pw[L * 72 + 32 + Q * 8];
#pragma unroll
        for (int dt = 0; dt < 4; ++dt) {
            int r = dt * 16 + L;
            bf16x8 vf0 = *(const bf16x8*)(Vs + (r * 8 + (Q ^ (r & 7))) * 8);
            bf16x8 vf1 = *(const bf16x8*)(Vs + (r * 8 + ((4 + Q) ^ (r & 7))) * 8);
            accO[dt] = __builtin_amdgcn_mfma_f32_16x16x32_bf16(pf0, vf0, accO[dt], 0, 0, 0);
            accO[dt] = __builtin_amdgcn_mfma_f32_16x16x32_bf16(pf1, vf1, accO[dt], 0, 0, 0);
        }
    }

    // ---- partial l: in-lane + cross-quad shfl
    lpart += __shfl_xor(lpart, 16, 64);
    lpart += __shfl_xor(lpart, 32, 64);
    if (Q == 0)
        laux[(((size_t)sp * 48 + bh) << 10) + iw + L] = lpart;

    // ---- accumulate unnormalized O partial (C-layout: col=d=L, row=Q*4+reg)
#pragma unroll
    for (int reg = 0; reg < 4; ++reg) {
        const size_t row = (size_t)b * NSeq + iw + Q * 4 + reg;
#pragma unroll
        for (int dt = 0; dt < 4; ++dt)
            atomicAdd(&Of[row * DIM + h * HD + dt * 16 + L], accO[dt][reg]);
    }
}

// ---------------------------------------------------------------------------
// Normalize: aout = bf16( Of / (l0+l1) )
__global__ __launch_bounds__(256) void combine_norm(
    const float* __restrict__ Of, const float* __restrict__ laux,
    short* __restrict__ aout)
{
    const int e4 = blockIdx.x * 256 + threadIdx.x;
    const size_t e = (size_t)e4 * 4;
    const int row = (int)(e / DIM);       // b*1024+i
    const int col = (int)(e % DIM);       // h*64+d
    const int b = row >> 10, i = row & 1023, h = col >> 6;
    const int bh = b * NH + h;
    const float l0 = laux[((size_t)bh << 10) + i];
    const float l1 = laux[((size_t)(48 + bh) << 10) + i];
    const float inv = 1.0f / (l0 + l1);
    float4 a = *(const float4*)(Of + e);
    short4 o = make_short4(f2b(a.x * inv), f2b(a.y * inv),
                           f2b(a.z * inv), f2b(a.w * inv));
    *(short4*)(aout + e) = o;
}

// ---------------------------------------------------------------------------
extern "C" void kernel_launch(void* const* d_in, const int* in_sizes, int n_in,
                              void* d_out, int out_size, void* d_ws, size_t ws_size,
                              hipStream_t stream)
{
    const float* x      = (const float*)d_in[0];
    const float* coords = (const float*)d_in[1];
    const float* elevp  = (const float*)d_in[2];
    const float* Wqkv   = (const float*)d_in[3];
    const float* Wproj  = (const float*)d_in[4];
    const float* bproj  = (const float*)d_in[5];
    const float* btab   = (const float*)d_in[6];
    const float* alpha  = (const float*)d_in[7];
    float* out = (float*)d_out;

    char* ws = (char*)d_ws;
    short* xb     = (short*)(ws);                        // 4096x768 bf16
    short* wqkvT  = (short*)(ws + 6291456);              // 2304x768 bf16
    short* wprojT = (short*)(ws + 9830400);              // 768x768 bf16
    short* qh     = (short*)(ws + 11010048);             // [48][1024][64]
    short* kh     = (short*)(ws + 17301504);
    short* vt     = (short*)(ws + 23592960);             // [48][64][1024]
    short* aout   = (short*)(ws + 29884416);             // 4096x768 bf16
    unsigned int* U = (unsigned int*)(ws + 36175872);    // 16.78 MB packed bias
    float* Of     = (float*)(ws + 52953088);             // 4096x768 fp32 (12.58 MB)
    float* laux   = (float*)(ws + 65536000);             // [2][48][1024] fp32
    // total ws use: 65,929,216 bytes

    const int M = 4 * NSeq;

    prep_kernel<<<dim3(PREP_TOT), 256, 0, stream>>>(
        x, xb, Wqkv, wqkvT, Wproj, wprojT, coords, elevp, alpha, U);

    hipMemsetAsync(Of, 0, (size_t)M * DIM * sizeof(float), stream);

    gemm_mfma<0><<<dim3(3 * DIM / 128, M / 64), 256, 0, stream>>>(
        xb, wqkvT, nullptr, nullptr, qh, kh, vt, M, 3 * DIM, DIM);

    attn_mfma<<<dim3(16, 4 * NH, 2), 256, 0, stream>>>(
        qh, kh, vt, U, btab, Of, laux);

    combine_norm<<<dim3(M * DIM / 1024), 256, 0, stream>>>(Of, laux, aout);

    gemm_mfma<1><<<dim3(DIM / 128, M / 64), 256, 0, stream>>>(
        aout, wprojT, bproj, out, nullptr, nullptr, nullptr, M, DIM, DIM);
}